// Round 10
// baseline (706.713 us; speedup 1.0000x reference)
//
#include <hip/hip_runtime.h>
#include <hip/hip_cooperative_groups.h>
#include <hip/hip_bf16.h>
#include <cstdint>

namespace cg = cooperative_groups;

// ---------------------------------------------------------------------------
// SingleHeadAttentionLayer: B=4, S=2048, D=KD=VD=1024, fp32 in/out.
// Round 10: ONE cooperative kernel, 5 phases with grid.sync() — r9 showed
// ~65 us of the 253 was dispatch-boundary overhead (5 serial dispatches).
// Algebra (r5+r9, both verified): scores = y@x^T + r1, y = x@M^T + w2,
//   M = Wk^T Wq, r1 = x@w1 + c, w1 = Wq^T bk, w2 = Wk^T bq, c = bq.bk
//   out = (P@U)/l + bo, U = x@Wvo^T + bvo, Wvo = Wo@Wv, bvo = bv@Wo^T
// Phases: P1 prep (10010 jobs) | P2 wcomb (128 tiles) | P3 y+U+r1 (1088)
//         P4 scores (544, exact-packed XCD pairs) | P5 pvo (512, heavy-first)
// Grid: min(1024, occ*256) & ~7, grid-stride loops (safe at any size).
// ---------------------------------------------------------------------------

#define BM 128

typedef __attribute__((ext_vector_type(8))) __bf16 bf16x8;
typedef __attribute__((ext_vector_type(4))) __bf16 bf16x4;
typedef __attribute__((ext_vector_type(4))) float floatx4;

struct KArgs {
  const float *x, *Wq, *bq, *Wk, *bk, *Wv, *bv, *Wo, *bo;
  float* out;
  __bf16 *xb, *yb, *Ut, *P, *Mqk, *Wvo, *Wqt, *Wkt, *Wvt, *Wob;
  float *lsum, *r1, *w1, *w2, *bvo, *cbuf;
};

__device__ __forceinline__ void async_copy16(const __bf16* g, const __bf16* l) {
  __builtin_amdgcn_global_load_lds(
      (const __attribute__((address_space(1))) unsigned int*)(const void*)g,
      (__attribute__((address_space(3))) unsigned int*)(unsigned)(uintptr_t)(const void*)l,
      16, 0, 0);
}

// 128x128 tile; K consumed 64/iter as two 32-panels in SM (verified pattern).
// SM partition: As0 SM[0:4096), As1 [4096:8192), Bs0 [8192:12288), Bs1 [12288:16384)
__device__ __forceinline__ void gemm_core(__bf16* SM, const __bf16* __restrict__ pA,
                                          const __bf16* __restrict__ pB,
                                          int K, int kBeg, int kEnd, int mb,
                                          int nb, floatx4 (&acc)[4][4]) {
  __bf16* As0 = SM;
  __bf16* As1 = SM + 4096;
  __bf16* Bs0 = SM + 8192;
  __bf16* Bs1 = SM + 12288;

  const int t = threadIdx.x;
  const int lane = t & 63;
  const int wave = t >> 6;
  const int quad = lane >> 4;
  const int l16 = lane & 15;
  const int wm = wave >> 1;
  const int wn = wave & 1;

  const __bf16* gA = pA + (long)(mb * BM + (t >> 2)) * K + ((t & 3) * 8);
  const __bf16* gB = pB + (long)(nb * BM + (t >> 2)) * K + ((t & 3) * 8);
  const long rowHalf = (long)64 * K;
  __bf16* lA0 = &As0[t * 8];
  __bf16* lA1 = &As1[t * 8];
  __bf16* lB0 = &Bs0[t * 8];
  __bf16* lB1 = &Bs1[t * 8];

  for (int kk = kBeg; kk < kEnd; ++kk) {
    const long ko = (long)kk * 64;
    async_copy16(gA + ko, lA0);
    async_copy16(gA + ko + rowHalf, lA0 + 2048);
    async_copy16(gA + ko + 32, lA1);
    async_copy16(gA + ko + 32 + rowHalf, lA1 + 2048);
    async_copy16(gB + ko, lB0);
    async_copy16(gB + ko + rowHalf, lB0 + 2048);
    async_copy16(gB + ko + 32, lB1);
    async_copy16(gB + ko + 32 + rowHalf, lB1 + 2048);
    __syncthreads();

#pragma unroll
    for (int p = 0; p < 2; ++p) {
      const __bf16* As = p ? As1 : As0;
      const __bf16* Bs = p ? Bs1 : Bs0;
      bf16x8 af[4], bfr[4];
#pragma unroll
      for (int i = 0; i < 4; ++i) {
        af[i] = *(const bf16x8*)&As[(wm * 64 + i * 16 + l16) * 32 + quad * 8];
        bfr[i] = *(const bf16x8*)&Bs[(wn * 64 + i * 16 + l16) * 32 + quad * 8];
      }
#pragma unroll
      for (int i = 0; i < 4; ++i)
#pragma unroll
        for (int j = 0; j < 4; ++j)
          acc[i][j] = __builtin_amdgcn_mfma_f32_16x16x32_bf16(af[i], bfr[j],
                                                              acc[i][j], 0, 0, 0);
    }
    __syncthreads();
  }
}

__device__ __forceinline__ float wave_sum(float s) {
  s += __shfl_xor(s, 1, 64);
  s += __shfl_xor(s, 2, 64);
  s += __shfl_xor(s, 4, 64);
  s += __shfl_xor(s, 8, 64);
  s += __shfl_xor(s, 16, 64);
  s += __shfl_xor(s, 32, 64);
  return s;
}

__global__ void __launch_bounds__(256, 2) coop(KArgs a) {
  __shared__ __align__(16) __bf16 SM[16384];  // 32 KB, shared by all phases
  const int t = threadIdx.x;
  const int gsz = gridDim.x;
  cg::grid_group grid = cg::this_grid();
  constexpr int S = 2048, D = 1024;

  // ============ P1: prep (10010 jobs) ============
  for (int bid = blockIdx.x; bid < 10010; bid += gsz) {
    if (bid < 8192) {  // cast x -> xb (8M elems)
      const long i = ((long)bid * 256 + t) * 4;
      const float4 f = *(const float4*)(a.x + i);
      bf16x4 o;
      o[0] = (__bf16)f.x; o[1] = (__bf16)f.y; o[2] = (__bf16)f.z; o[3] = (__bf16)f.w;
      *(bf16x4*)(a.xb + i) = o;
    } else if (bid < 8960) {  // transpose-cast Wq,Wk,Wv (256 64x64 tiles each)
      const int which = (bid - 8192) >> 8;
      const int idx = (bid - 8192) & 255;
      const float* src = which == 0 ? a.Wq : (which == 1 ? a.Wk : a.Wv);
      __bf16* dst = which == 0 ? a.Wqt : (which == 1 ? a.Wkt : a.Wvt);
      const int r0 = (idx >> 4) * 64, c0 = (idx & 15) * 64;
      __bf16(*tile)[66] = reinterpret_cast<__bf16(*)[66]>(SM);
      __syncthreads();
#pragma unroll
      for (int e = 0; e < 16; ++e) {
        const int i = e * 256 + t;
        const int r = i >> 6, c = i & 63;
        tile[r][c] = (__bf16)src[(long)(r0 + r) * 1024 + (c0 + c)];
      }
      __syncthreads();
#pragma unroll
      for (int e = 0; e < 16; ++e) {
        const int i = e * 256 + t;
        const int r = i >> 6, c = i & 63;
        dst[(long)(c0 + r) * 1024 + (r0 + c)] = tile[c][r];
      }
      __syncthreads();
    } else if (bid < 9984) {  // cast Wo -> Wob (1M elems)
      const long i = ((long)(bid - 8960) * 256 + t) * 4;
      const float4 f = *(const float4*)(a.Wo + i);
      bf16x4 o;
      o[0] = (__bf16)f.x; o[1] = (__bf16)f.y; o[2] = (__bf16)f.z; o[3] = (__bf16)f.w;
      *(bf16x4*)(a.Wob + i) = o;
    } else if (bid < 9992) {  // bvo[d] = Wo[d].bv, 8 jobs x 128 rows
      const int lane = t & 63, wave = t >> 6;
      for (int rr = 0; rr < 32; ++rr) {
        const int row = (bid - 9984) * 128 + wave * 32 + rr;
        float s = 0.f;
        for (int v = lane; v < 1024; v += 64) s += a.bv[v] * a.Wo[(long)row * 1024 + v];
        s = wave_sum(s);
        if (lane == 0) a.bvo[row] = s;
      }
    } else if (bid < 10008) {  // w1[d]=sum_kd Wq[kd][d]bk[kd] / w2 with Wk,bq
      const bool is1 = bid < 10000;
      const int jb = is1 ? (bid - 9992) : (bid - 10000);
      const float* W = is1 ? a.Wq : a.Wk;
      const float* bb = is1 ? a.bk : a.bq;
      float* ow = is1 ? a.w1 : a.w2;
      const int d = jb * 128 + (t & 127);
      const int half = t >> 7;
      float s = 0.f;
      for (int kd = half * 512; kd < half * 512 + 512; ++kd)
        s += W[(long)kd * 1024 + d] * bb[kd];
      float* fbuf = (float*)SM;
      __syncthreads();
      fbuf[t] = s;
      __syncthreads();
      if (t < 128) ow[jb * 128 + t] = fbuf[t] + fbuf[t + 128];
      __syncthreads();
    } else if (bid == 10008) {  // c = bq.bk
      float s = 0.f;
      for (int i = t; i < 1024; i += 256) s += a.bq[i] * a.bk[i];
      s = wave_sum(s);
      float* fbuf = (float*)SM;
      __syncthreads();
      if ((t & 63) == 0) fbuf[t >> 6] = s;
      __syncthreads();
      if (t == 0) a.cbuf[0] = fbuf[0] + fbuf[1] + fbuf[2] + fbuf[3];
      __syncthreads();
    } else {  // zero lsum (8192 floats)
#pragma unroll
      for (int e = 0; e < 8; ++e)
        *(float4*)(a.lsum + (e * 256 + t) * 4) = float4{0.f, 0.f, 0.f, 0.f};
    }
  }
  __threadfence();
  grid.sync();

  // ============ P2: wcomb — M = Wk^T@Wq (64), Wvo = Wo@Wv (64) ============
  for (int j = blockIdx.x; j < 128; j += gsz) {
    const bool isM = j < 64;
    const int wid = isM ? j : (j - 64);
    const int mb = wid >> 3, nb = wid & 7;
    const __bf16* pA = isM ? a.Wkt : a.Wob;
    const __bf16* pB = isM ? a.Wqt : a.Wvt;
    __bf16* C = isM ? a.Mqk : a.Wvo;
    floatx4 acc[4][4] = {};
    gemm_core(SM, pA, pB, 1024, 0, 16, mb, nb, acc);
    const int lane = t & 63, wave = t >> 6;
    const int rb = (wave >> 1) * 64 + (lane >> 4) * 4;
    const int cb = (wave & 1) * 64 + (lane & 15);
#pragma unroll
    for (int j4 = 0; j4 < 4; ++j4) {
      const int gc = nb * 128 + cb + j4 * 16;
#pragma unroll
      for (int i = 0; i < 4; ++i) {
        const int gr = mb * BM + rb + i * 16;
#pragma unroll
        for (int r = 0; r < 4; ++r)
          C[(long)(gr + r) * 1024 + gc] = (__bf16)acc[i][j4][r];
      }
    }
  }
  __threadfence();
  grid.sync();

  // ============ P3: y (512) + U (512) + r1 (64) ============
  for (int j = blockIdx.x; j < 1088; j += gsz) {
    if (j < 1024) {
      const bool isY = j < 512;
      const int pid = isY ? j : (j - 512);
      const int xcd = pid & 7;
      const int jj = pid >> 3;
      const int mb = xcd * 8 + (jj & 7);
      const int nb = jj >> 3;
      const __bf16* pB = isY ? a.Mqk : a.Wvo;
      floatx4 acc[4][4] = {};
      gemm_core(SM, a.xb, pB, D, 0, D / 64, mb, nb, acc);
      const int lane = t & 63, wave = t >> 6;
      const int rb = (wave >> 1) * 64 + (lane >> 4) * 4;
      const int cb = (wave & 1) * 64 + (lane & 15);
      if (isY) {  // y = x@M^T + w2
#pragma unroll
        for (int j4 = 0; j4 < 4; ++j4) {
          const int gc = nb * 128 + cb + j4 * 16;
          const float bv = a.w2[gc];
#pragma unroll
          for (int i = 0; i < 4; ++i) {
            const int gr = mb * BM + rb + i * 16;
#pragma unroll
            for (int r = 0; r < 4; ++r)
              a.yb[(long)(gr + r) * D + gc] = (__bf16)(acc[i][j4][r] + bv);
          }
        }
      } else {  // Ut[bb][dout][s] = U[bb][s][dout]
        const int bb = (mb * BM) / S;
        const int s0 = mb * BM - bb * S;
#pragma unroll
        for (int j4 = 0; j4 < 4; ++j4) {
          const int gc = nb * 128 + cb + j4 * 16;
          const float bv = a.bvo[gc];
#pragma unroll
          for (int i = 0; i < 4; ++i) {
            const int sr = s0 + rb + i * 16;
            bf16x4 o;
#pragma unroll
            for (int r = 0; r < 4; ++r) o[r] = (__bf16)(acc[i][j4][r] + bv);
            *(bf16x4*)&a.Ut[((long)bb * D + gc) * S + sr] = o;
          }
        }
      }
    } else {  // r1[row] = xb[row].w1 + c
      const int jb = j - 1024;
      const float c = a.cbuf[0];
      const int lane = t & 63, wave = t >> 6;
      for (int rr = 0; rr < 32; ++rr) {
        const int row = jb * 128 + wave * 32 + rr;
        const bf16x8 a0 = *(const bf16x8*)&a.xb[(long)row * D + lane * 16];
        const bf16x8 a1 = *(const bf16x8*)&a.xb[(long)row * D + lane * 16 + 8];
        float s = 0.f;
#pragma unroll
        for (int e = 0; e < 8; ++e) {
          s += (float)a0[e] * a.w1[lane * 16 + e];
          s += (float)a1[e] * a.w1[lane * 16 + 8 + e];
        }
        s = wave_sum(s);
        if (lane == 0) a.r1[row] = s + c;
      }
    }
  }
  __threadfence();
  grid.sync();

  // ============ P4: scores P = exp(|y@x^T + r1|/32) causal + rowsums =======
  for (int j = blockIdx.x; j < 544; j += gsz) {
    const int xcd = j & 7;
    const int r = j >> 3;  // 0..67
    const int b = r / 17;
    const int ci = r - b * 17;
    const int n1 = xcd + 1;
    const int mb = (ci < n1) ? xcd : (15 - xcd);
    const int nb = (ci < n1) ? ci : (ci - n1);
    floatx4 acc[4][4] = {};
    gemm_core(SM, a.yb + (long)b * S * D, a.xb + (long)b * S * D, D, 0, D / 64,
              mb, nb, acc);
    const int lane = t & 63, wave = t >> 6;
    const int l16 = lane & 15;
    const int rb = (wave >> 1) * 64 + (lane >> 4) * 4;
    const int cb = (wave & 1) * 64 + l16;
    __bf16* C = a.P + (long)b * S * S;
    float* lrow = a.lsum + (long)b * S;
    const float* r1b = a.r1 + (long)b * S;
    const float sc = 0.03125f;
#pragma unroll
    for (int i = 0; i < 4; ++i) {
#pragma unroll
      for (int r_ = 0; r_ < 4; ++r_) {
        const int row = mb * BM + rb + i * 16 + r_;
        const float rv = r1b[row];
        float psum = 0.f;
#pragma unroll
        for (int j4 = 0; j4 < 4; ++j4) {
          const int col = nb * 128 + cb + j4 * 16;
          const float p =
              (col <= row) ? __expf(fabsf((acc[i][j4][r_] + rv) * sc)) : 0.f;
          psum += p;
          C[(long)row * S + col] = (__bf16)p;
        }
        psum += __shfl_xor(psum, 1, 64);
        psum += __shfl_xor(psum, 2, 64);
        psum += __shfl_xor(psum, 4, 64);
        psum += __shfl_xor(psum, 8, 64);
        if (l16 == 0) atomicAdd(&lrow[row], psum);
      }
    }
  }
  __threadfence();
  grid.sync();

  // ============ P5: out = (P@U)/l + bo (heavy-first pair balance) ==========
  for (int j = blockIdx.x; j < 512; j += gsz) {
    const int xcd = j & 7;
    const int jj = j >> 3;  // 0..63
    const int half = jj >> 5;
    const int idx = jj & 31;
    const int b = idx >> 3;
    const int nb = idx & 7;
    const int mb = half ? xcd : (15 - xcd);
    floatx4 acc[4][4] = {};
    gemm_core(SM, a.P + (long)b * S * S, a.Ut + (long)b * D * S, S, 0,
              2 * (mb + 1), mb, nb, acc);
    const int lane = t & 63, wave = t >> 6;
    const int rb = (wave >> 1) * 64 + (lane >> 4) * 4;
    const int cb = (wave & 1) * 64 + (lane & 15);
    const float* lrow = a.lsum + (long)b * S;
#pragma unroll
    for (int i = 0; i < 4; ++i) {
#pragma unroll
      for (int r_ = 0; r_ < 4; ++r_) {
        const int row = mb * BM + rb + i * 16 + r_;
        const float inv = 1.f / lrow[row];
#pragma unroll
        for (int j4 = 0; j4 < 4; ++j4) {
          const int col = nb * 128 + cb + j4 * 16;
          a.out[((long)b * S + row) * D + col] = acc[i][j4][r_] * inv + a.bo[col];
        }
      }
    }
  }
}

extern "C" void kernel_launch(void* const* d_in, const int* in_sizes, int n_in,
                              void* d_out, int out_size, void* d_ws, size_t ws_size,
                              hipStream_t stream) {
  constexpr long MB_ = 1024 * 1024;
  char* w = (char*)d_ws;

  KArgs ka;
  ka.x = (const float*)d_in[0];
  ka.Wq = (const float*)d_in[1];
  ka.bq = (const float*)d_in[2];
  ka.Wk = (const float*)d_in[3];
  ka.bk = (const float*)d_in[4];
  ka.Wv = (const float*)d_in[5];
  ka.bv = (const float*)d_in[6];
  ka.Wo = (const float*)d_in[7];
  ka.bo = (const float*)d_in[8];
  ka.out = (float*)d_out;
  ka.xb = (__bf16*)(w);
  ka.yb = (__bf16*)(w + 16 * MB_);
  ka.Ut = (__bf16*)(w + 32 * MB_);
  ka.P = (__bf16*)(w + 48 * MB_);
  ka.Mqk = (__bf16*)(w + 80 * MB_);
  ka.Wvo = (__bf16*)(w + 82 * MB_);
  ka.Wqt = (__bf16*)(w + 84 * MB_);
  ka.Wkt = (__bf16*)(w + 86 * MB_);
  ka.Wvt = (__bf16*)(w + 88 * MB_);
  ka.Wob = (__bf16*)(w + 90 * MB_);
  ka.lsum = (float*)(w + 92 * MB_);
  ka.r1 = (float*)(w + 92 * MB_ + 32768);
  ka.w1 = (float*)(w + 92 * MB_ + 65536);
  ka.w2 = (float*)(w + 92 * MB_ + 69632);
  ka.bvo = (float*)(w + 92 * MB_ + 73728);
  ka.cbuf = (float*)(w + 92 * MB_ + 77824);

  // co-residency-safe grid: query occupancy, clamp to 1024, multiple of 8
  int occ = 0;
  (void)hipOccupancyMaxActiveBlocksPerMultiprocessor(&occ, coop, 256, 0);
  if (occ < 1) occ = 1;
  long grid = (long)occ * 256;
  if (grid > 1024) grid = 1024;
  grid &= ~7L;
  if (grid < 8) grid = 8;

  void* args[] = {(void*)&ka};
  (void)hipLaunchCooperativeKernel(coop, dim3((unsigned)grid), dim3(256), args,
                                   0, stream);
}